// Round 1
// baseline (2306.067 us; speedup 1.0000x reference)
//
#include <hip/hip_runtime.h>

// Problem constants (match reference)
static constexpr int DIM = 128;
static constexpr int N = DIM * DIM * DIM;        // 2,097,152 voxels
static constexpr int ITERS = 20;
static constexpr float EPS = 1e-6f;

// Normalized Gaussian(sigma=1, radius=3) weights, computed in double, rounded.
__constant__ float c_gw[7] = {
    0.00443305f, 0.05400559f, 0.24203624f, 0.39905028f,
    0.24203624f, 0.05400559f, 0.00443305f
};

__device__ __forceinline__ int clamp_i(int v, int lo, int hi) {
    return min(max(v, lo), hi);
}

// Trilinear warp: out[z,y,x] = moving sampled at (z+vf0, y+vf1, x+vf2),
// map_coordinates order=1 mode='nearest' semantics (clamped indices).
__global__ void warp_kernel(const float* __restrict__ mov,
                            const float* __restrict__ vf,
                            float* __restrict__ out) {
    int idx = blockIdx.x * blockDim.x + threadIdx.x;
    if (idx >= N) return;
    int x = idx & 127, y = (idx >> 7) & 127, z = idx >> 14;

    float cz = (float)z + vf[idx];
    float cy = (float)y + vf[N + idx];
    float cx = (float)x + vf[2 * N + idx];

    float flz = floorf(cz), fly = floorf(cy), flx = floorf(cx);
    float fz = cz - flz, fy = cy - fly, fx = cx - flx;

    int z0 = (int)flz, y0 = (int)fly, x0 = (int)flx;
    int z0c = clamp_i(z0, 0, DIM - 1), z1c = clamp_i(z0 + 1, 0, DIM - 1);
    int y0c = clamp_i(y0, 0, DIM - 1), y1c = clamp_i(y0 + 1, 0, DIM - 1);
    int x0c = clamp_i(x0, 0, DIM - 1), x1c = clamp_i(x0 + 1, 0, DIM - 1);

    int b00 = (z0c << 14) + (y0c << 7);
    int b01 = (z0c << 14) + (y1c << 7);
    int b10 = (z1c << 14) + (y0c << 7);
    int b11 = (z1c << 14) + (y1c << 7);

    float v000 = mov[b00 + x0c], v001 = mov[b00 + x1c];
    float v010 = mov[b01 + x0c], v011 = mov[b01 + x1c];
    float v100 = mov[b10 + x0c], v101 = mov[b10 + x1c];
    float v110 = mov[b11 + x0c], v111 = mov[b11 + x1c];

    float c00 = v000 + fx * (v001 - v000);
    float c01 = v010 + fx * (v011 - v010);
    float c10 = v100 + fx * (v101 - v100);
    float c11 = v110 + fx * (v111 - v110);
    float c0 = c00 + fy * (c01 - c00);
    float c1 = c10 + fy * (c11 - c10);
    out[idx] = c0 + fz * (c1 - c0);
}

// Demon forces (dual): u = vf + tau * f, tau=1.
// g = 0.5*(grad(warped) + grad(fixed)), jnp.gradient boundary rules.
__global__ void forces_kernel(const float* __restrict__ wpd,
                              const float* __restrict__ fix,
                              const float* __restrict__ vf,
                              float* __restrict__ u) {
    int idx = blockIdx.x * blockDim.x + threadIdx.x;
    if (idx >= N) return;
    int x = idx & 127, y = (idx >> 7) & 127, z = idx >> 14;

    float wc = wpd[idx], fc = fix[idx];
    float diff = wc - fc;

    float gz, gy, gx;
    // z axis (stride 16384)
    {
        float gw, gf;
        if (z == 0)            { gw = wpd[idx + 16384] - wc;  gf = fix[idx + 16384] - fc; }
        else if (z == DIM - 1) { gw = wc - wpd[idx - 16384];  gf = fc - fix[idx - 16384]; }
        else { gw = 0.5f * (wpd[idx + 16384] - wpd[idx - 16384]);
               gf = 0.5f * (fix[idx + 16384] - fix[idx - 16384]); }
        gz = 0.5f * (gw + gf);
    }
    // y axis (stride 128)
    {
        float gw, gf;
        if (y == 0)            { gw = wpd[idx + 128] - wc;  gf = fix[idx + 128] - fc; }
        else if (y == DIM - 1) { gw = wc - wpd[idx - 128];  gf = fc - fix[idx - 128]; }
        else { gw = 0.5f * (wpd[idx + 128] - wpd[idx - 128]);
               gf = 0.5f * (fix[idx + 128] - fix[idx - 128]); }
        gy = 0.5f * (gw + gf);
    }
    // x axis (stride 1)
    {
        float gw, gf;
        if (x == 0)            { gw = wpd[idx + 1] - wc;  gf = fix[idx + 1] - fc; }
        else if (x == DIM - 1) { gw = wc - wpd[idx - 1];  gf = fc - fix[idx - 1]; }
        else { gw = 0.5f * (wpd[idx + 1] - wpd[idx - 1]);
               gf = 0.5f * (fix[idx + 1] - fix[idx - 1]); }
        gx = 0.5f * (gw + gf);
    }

    float denom = gz * gz + gy * gy + gx * gx + diff * diff;
    float s = (denom > EPS) ? (diff / denom) : 0.0f;

    u[idx]         = vf[idx]         + s * gz;
    u[N + idx]     = vf[N + idx]     + s * gy;
    u[2 * N + idx] = vf[2 * N + idx] + s * gx;
}

// Separable 7-tap Gaussian along one axis, zero padding.
// STRIDE: 1 (W), 128 (H), 16384 (D). Operates on 3 channels (3N threads).
template <int STRIDE>
__global__ void smooth_kernel(const float* __restrict__ in,
                              float* __restrict__ out) {
    int tid = blockIdx.x * blockDim.x + threadIdx.x;
    if (tid >= 3 * N) return;
    int v = tid & (N - 1);  // voxel index within channel
    int p;                  // coordinate along the smoothing axis
    if (STRIDE == 1)        p = v & 127;
    else if (STRIDE == 128) p = (v >> 7) & 127;
    else                    p = v >> 14;

    float acc = 0.0f;
#pragma unroll
    for (int t = -3; t <= 3; ++t) {
        int q = p + t;
        if (q >= 0 && q < DIM) acc += c_gw[t + 3] * in[tid + t * STRIDE];
    }
    out[tid] = acc;
}

extern "C" void kernel_launch(void* const* d_in, const int* in_sizes, int n_in,
                              void* d_out, int out_size, void* d_ws, size_t ws_size,
                              hipStream_t stream) {
    const float* mov = (const float*)d_in[0];
    const float* fix = (const float*)d_in[1];
    float* vf = (float*)d_out;          // (3, N) — lives in d_out throughout
    float* ws = (float*)d_ws;
    float* warped = ws;                 // N floats
    float* u      = ws + (size_t)N;     // 3N floats
    float* tmp    = ws + (size_t)4 * N; // 3N floats

    // vf0 = 0 (harness poisons d_out with 0xAA before every call)
    hipMemsetAsync(vf, 0, (size_t)3 * N * sizeof(float), stream);

    const int BLK = 256;
    const int gridN  = N / BLK;          // 8192
    const int grid3N = 3 * N / BLK;      // 24576

    for (int it = 0; it < ITERS; ++it) {
        warp_kernel<<<gridN, BLK, 0, stream>>>(mov, vf, warped);
        forces_kernel<<<gridN, BLK, 0, stream>>>(warped, fix, vf, u);
        smooth_kernel<1>    <<<grid3N, BLK, 0, stream>>>(u, tmp);
        smooth_kernel<128>  <<<grid3N, BLK, 0, stream>>>(tmp, u);
        smooth_kernel<16384><<<grid3N, BLK, 0, stream>>>(u, vf);
    }
}

// Round 2
// 2280.757 us; speedup vs baseline: 1.0111x; 1.0111x over previous
//
#include <hip/hip_runtime.h>

// Problem constants (match reference)
static constexpr int DIM = 128;
static constexpr int N = DIM * DIM * DIM;        // 2,097,152 voxels
static constexpr int ITERS = 20;
static constexpr float EPS = 1e-6f;

// Gaussian(sigma=1, radius=3) normalized weights
#define W0 0.39905028f
#define W1 0.24203624f
#define W2 0.05400559f
#define W3 0.00443305f

__device__ __forceinline__ int clamp_i(int v, int lo, int hi) {
    return min(max(v, lo), hi);
}

// ---------------------------------------------------------------------------
// Trilinear warp: out[z,y,x] = moving sampled at (z+vf0, y+vf1, x+vf2),
// map_coordinates order=1 mode='nearest' semantics (clamped indices).
// ---------------------------------------------------------------------------
__global__ void warp_kernel(const float* __restrict__ mov,
                            const float* __restrict__ vf,
                            float* __restrict__ out) {
    int idx = blockIdx.x * blockDim.x + threadIdx.x;
    if (idx >= N) return;
    int x = idx & 127, y = (idx >> 7) & 127, z = idx >> 14;

    float cz = (float)z + vf[idx];
    float cy = (float)y + vf[N + idx];
    float cx = (float)x + vf[2 * N + idx];

    float flz = floorf(cz), fly = floorf(cy), flx = floorf(cx);
    float fz = cz - flz, fy = cy - fly, fx = cx - flx;

    int z0 = (int)flz, y0 = (int)fly, x0 = (int)flx;
    int z0c = clamp_i(z0, 0, DIM - 1), z1c = clamp_i(z0 + 1, 0, DIM - 1);
    int y0c = clamp_i(y0, 0, DIM - 1), y1c = clamp_i(y0 + 1, 0, DIM - 1);
    int x0c = clamp_i(x0, 0, DIM - 1), x1c = clamp_i(x0 + 1, 0, DIM - 1);

    int b00 = (z0c << 14) + (y0c << 7);
    int b01 = (z0c << 14) + (y1c << 7);
    int b10 = (z1c << 14) + (y0c << 7);
    int b11 = (z1c << 14) + (y1c << 7);

    float v000 = mov[b00 + x0c], v001 = mov[b00 + x1c];
    float v010 = mov[b01 + x0c], v011 = mov[b01 + x1c];
    float v100 = mov[b10 + x0c], v101 = mov[b10 + x1c];
    float v110 = mov[b11 + x0c], v111 = mov[b11 + x1c];

    float c00 = v000 + fx * (v001 - v000);
    float c01 = v010 + fx * (v011 - v010);
    float c10 = v100 + fx * (v101 - v100);
    float c11 = v110 + fx * (v111 - v110);
    float c0 = c00 + fy * (c01 - c00);
    float c1 = c10 + fy * (c11 - c10);
    out[idx] = c0 + fz * (c1 - c0);
}

// ---------------------------------------------------------------------------
// Demon forces (dual), float4 over x: u = vf + diff*g/(|g|^2+diff^2).
// g = 0.5*(grad(warped)+grad(fixed)), jnp.gradient boundary rules.
// ---------------------------------------------------------------------------
__global__ void forces_kernel(const float* __restrict__ wpd,
                              const float* __restrict__ fix,
                              const float* __restrict__ vf,
                              float* __restrict__ u) {
    int t = blockIdx.x * blockDim.x + threadIdx.x;
    if (t >= N / 4) return;
    int idx = t << 2;
    int x0 = idx & 127, y = (idx >> 7) & 127, z = idx >> 14;

    float4 wc4 = *(const float4*)(wpd + idx);
    float4 fc4 = *(const float4*)(fix + idx);

    int iyp = (y < 127) ? idx + 128   : idx;
    int iym = (y > 0)   ? idx - 128   : idx;
    int izp = (z < 127) ? idx + 16384 : idx;
    int izm = (z > 0)   ? idx - 16384 : idx;

    float4 wyp = *(const float4*)(wpd + iyp), wym = *(const float4*)(wpd + iym);
    float4 wzp = *(const float4*)(wpd + izp), wzm = *(const float4*)(wpd + izm);
    float4 fyp = *(const float4*)(fix + iyp), fym = *(const float4*)(fix + iym);
    float4 fzp = *(const float4*)(fix + izp), fzm = *(const float4*)(fix + izm);

    float wl = (x0 > 0)   ? wpd[idx - 1] : 0.0f;
    float wr = (x0 < 124) ? wpd[idx + 4] : 0.0f;
    float fl = (x0 > 0)   ? fix[idx - 1] : 0.0f;
    float fr = (x0 < 124) ? fix[idx + 4] : 0.0f;

    float wcv[4] = {wc4.x, wc4.y, wc4.z, wc4.w};
    float fcv[4] = {fc4.x, fc4.y, fc4.z, fc4.w};
    float wypv[4] = {wyp.x, wyp.y, wyp.z, wyp.w};
    float wymv[4] = {wym.x, wym.y, wym.z, wym.w};
    float wzpv[4] = {wzp.x, wzp.y, wzp.z, wzp.w};
    float wzmv[4] = {wzm.x, wzm.y, wzm.z, wzm.w};
    float fypv[4] = {fyp.x, fyp.y, fyp.z, fyp.w};
    float fymv[4] = {fym.x, fym.y, fym.z, fym.w};
    float fzpv[4] = {fzp.x, fzp.y, fzp.z, fzp.w};
    float fzmv[4] = {fzm.x, fzm.y, fzm.z, fzm.w};

    float4 vz4 = *(const float4*)(vf + idx);
    float4 vy4 = *(const float4*)(vf + N + idx);
    float4 vx4 = *(const float4*)(vf + 2 * N + idx);
    float vzv[4] = {vz4.x, vz4.y, vz4.z, vz4.w};
    float vyv[4] = {vy4.x, vy4.y, vy4.z, vy4.w};
    float vxv[4] = {vx4.x, vx4.y, vx4.z, vx4.w};

    float oz[4], oy[4], ox[4];
#pragma unroll
    for (int i = 0; i < 4; ++i) {
        float wc = wcv[i], fc = fcv[i];
        float diff = wc - fc;

        // z gradient (uniform case across pack)
        float gwz = (z == 0)   ? (wzpv[i] - wc)
                  : (z == 127) ? (wc - wzmv[i])
                  : 0.5f * (wzpv[i] - wzmv[i]);
        float gfz = (z == 0)   ? (fzpv[i] - fc)
                  : (z == 127) ? (fc - fzmv[i])
                  : 0.5f * (fzpv[i] - fzmv[i]);
        float gz = 0.5f * (gwz + gfz);

        // y gradient
        float gwy = (y == 0)   ? (wypv[i] - wc)
                  : (y == 127) ? (wc - wymv[i])
                  : 0.5f * (wypv[i] - wymv[i]);
        float gfy = (y == 0)   ? (fypv[i] - fc)
                  : (y == 127) ? (fc - fymv[i])
                  : 0.5f * (fypv[i] - fymv[i]);
        float gy = 0.5f * (gwy + gfy);

        // x gradient (per-element neighbors within / beyond the pack)
        float wleft  = (i == 0) ? wl : wcv[i - 1];
        float wright = (i == 3) ? wr : wcv[i + 1];
        float fleft  = (i == 0) ? fl : fcv[i - 1];
        float fright = (i == 3) ? fr : fcv[i + 1];
        int xi = x0 + i;
        float gwx = (xi == 0)   ? (wright - wc)
                  : (xi == 127) ? (wc - wleft)
                  : 0.5f * (wright - wleft);
        float gfx = (xi == 0)   ? (fright - fc)
                  : (xi == 127) ? (fc - fleft)
                  : 0.5f * (fright - fleft);
        float gx = 0.5f * (gwx + gfx);

        float denom = gz * gz + gy * gy + gx * gx + diff * diff;
        float s = (denom > EPS) ? (diff / denom) : 0.0f;

        oz[i] = vzv[i] + s * gz;
        oy[i] = vyv[i] + s * gy;
        ox[i] = vxv[i] + s * gx;
    }

    *(float4*)(u + idx)         = make_float4(oz[0], oz[1], oz[2], oz[3]);
    *(float4*)(u + N + idx)     = make_float4(oy[0], oy[1], oy[2], oy[3]);
    *(float4*)(u + 2 * N + idx) = make_float4(ox[0], ox[1], ox[2], ox[3]);
}

// ---------------------------------------------------------------------------
// Fused separable 3D Gaussian blur (zero padding), one kernel, LDS-tiled.
// 16^3 output tile per block; x-blur global->LDS, y-blur LDS->LDS,
// z-blur LDS->global. Blur order (x,y,z) commutes with reference (z,y,x).
// LDS: B 22*22*16 (30.9KB) + C 22*16*16 (22.5KB) = 53.5KB -> 3 blocks/CU.
// ---------------------------------------------------------------------------
#define TILE 16
#define HALO 3
#define HB (TILE + 2 * HALO)   // 22

__global__ __launch_bounds__(256) void smooth3d_kernel(const float* __restrict__ in,
                                                       float* __restrict__ out) {
    int b = blockIdx.x;
    int c = b >> 9;            // channel 0..2  (512 tiles per channel)
    int t = b & 511;
    int tx = (t & 7) << 4;
    int ty = ((t >> 3) & 7) << 4;
    int tz = (t >> 6) << 4;
    const float* inc = in + (size_t)c * N;
    float* outc = out + (size_t)c * N;

    __shared__ float B[HB * HB * TILE];    // [zz][yy][x]
    __shared__ float C[HB * TILE * TILE];  // [zz][y][x]

    const float gw[7] = {W3, W2, W1, W0, W1, W2, W3};

    // Stage 1: x-blur from global into B (zero rows for out-of-volume y/z)
    for (int e = threadIdx.x; e < HB * HB * TILE; e += 256) {
        int x = e & 15;
        int r = e >> 4;
        int yy = r % HB;
        int zz = r / HB;
        int gz = tz + zz - HALO, gy = ty + yy - HALO, gx = tx + x;
        float acc = 0.0f;
        if (gz >= 0 && gz < DIM && gy >= 0 && gy < DIM) {
            const float* row = inc + ((size_t)gz << 14) + (gy << 7);
#pragma unroll
            for (int j = -3; j <= 3; ++j) {
                int q = gx + j;
                if (q >= 0 && q < DIM) acc += gw[j + 3] * row[q];
            }
        }
        B[e] = acc;
    }
    __syncthreads();

    // Stage 2: y-blur B -> C
    for (int e = threadIdx.x; e < HB * TILE * TILE; e += 256) {
        int x = e & 15;
        int y = (e >> 4) & 15;
        int zz = e >> 8;
        int base = (zz * HB + y) * TILE + x;   // B[zz][y+j][x]
        float acc = 0.0f;
#pragma unroll
        for (int j = 0; j < 7; ++j) acc += gw[j] * B[base + j * TILE];
        C[e] = acc;
    }
    __syncthreads();

    // Stage 3: z-blur C -> global
    for (int e = threadIdx.x; e < TILE * TILE * TILE; e += 256) {
        int x = e & 15;
        int y = (e >> 4) & 15;
        int z = e >> 8;
        int base = (z * TILE + y) * TILE + x;  // C[z+j][y][x]
        float acc = 0.0f;
#pragma unroll
        for (int j = 0; j < 7; ++j) acc += gw[j] * C[base + j * TILE * TILE];
        int gz = tz + z, gy = ty + y, gx = tx + x;
        outc[((size_t)gz << 14) + (gy << 7) + gx] = acc;
    }
}

extern "C" void kernel_launch(void* const* d_in, const int* in_sizes, int n_in,
                              void* d_out, int out_size, void* d_ws, size_t ws_size,
                              hipStream_t stream) {
    const float* mov = (const float*)d_in[0];
    const float* fix = (const float*)d_in[1];
    float* vf = (float*)d_out;          // (3, N) — lives in d_out throughout
    float* ws = (float*)d_ws;
    float* warped = ws;                 // N floats
    float* u      = ws + (size_t)N;     // 3N floats

    // vf0 = 0 (harness poisons d_out with 0xAA before every call)
    hipMemsetAsync(vf, 0, (size_t)3 * N * sizeof(float), stream);

    const int BLK = 256;
    const int gridN  = N / BLK;          // 8192
    const int gridF  = (N / 4) / BLK;    // 2048
    const int gridS  = 512 * 3;          // 1536 tiles

    for (int it = 0; it < ITERS; ++it) {
        warp_kernel  <<<gridN, BLK, 0, stream>>>(mov, vf, warped);
        forces_kernel<<<gridF, BLK, 0, stream>>>(warped, fix, vf, u);
        smooth3d_kernel<<<gridS, BLK, 0, stream>>>(u, vf);
    }
}

// Round 4
// 1059.535 us; speedup vs baseline: 2.1765x; 2.1526x over previous
//
#include <hip/hip_runtime.h>

// Problem constants (match reference)
static constexpr int DIM = 128;
static constexpr int N = DIM * DIM * DIM;        // 2,097,152 voxels
static constexpr int ITERS = 20;
static constexpr float EPS = 1e-6f;

// Gaussian(sigma=1, radius=3) normalized weights
#define W0 0.39905028f
#define W1 0.24203624f
#define W2 0.05400559f
#define W3 0.00443305f

__device__ __forceinline__ int clamp_i(int v, int lo, int hi) {
    return min(max(v, lo), hi);
}

// ---------------------------------------------------------------------------
// Trilinear warp: out[z,y,x] = moving sampled at (z+vf0, y+vf1, x+vf2),
// map_coordinates order=1 mode='nearest' semantics (clamped indices).
// ---------------------------------------------------------------------------
__global__ void warp_kernel(const float* __restrict__ mov,
                            const float* __restrict__ vf,
                            float* __restrict__ out) {
    int idx = blockIdx.x * blockDim.x + threadIdx.x;
    if (idx >= N) return;
    int x = idx & 127, y = (idx >> 7) & 127, z = idx >> 14;

    float cz = (float)z + vf[idx];
    float cy = (float)y + vf[N + idx];
    float cx = (float)x + vf[2 * N + idx];

    float flz = floorf(cz), fly = floorf(cy), flx = floorf(cx);
    float fz = cz - flz, fy = cy - fly, fx = cx - flx;

    int z0 = (int)flz, y0 = (int)fly, x0 = (int)flx;
    int z0c = clamp_i(z0, 0, DIM - 1), z1c = clamp_i(z0 + 1, 0, DIM - 1);
    int y0c = clamp_i(y0, 0, DIM - 1), y1c = clamp_i(y0 + 1, 0, DIM - 1);
    int x0c = clamp_i(x0, 0, DIM - 1), x1c = clamp_i(x0 + 1, 0, DIM - 1);

    int b00 = (z0c << 14) + (y0c << 7);
    int b01 = (z0c << 14) + (y1c << 7);
    int b10 = (z1c << 14) + (y0c << 7);
    int b11 = (z1c << 14) + (y1c << 7);

    float v000 = mov[b00 + x0c], v001 = mov[b00 + x1c];
    float v010 = mov[b01 + x0c], v011 = mov[b01 + x1c];
    float v100 = mov[b10 + x0c], v101 = mov[b10 + x1c];
    float v110 = mov[b11 + x0c], v111 = mov[b11 + x1c];

    float c00 = v000 + fx * (v001 - v000);
    float c01 = v010 + fx * (v011 - v010);
    float c10 = v100 + fx * (v101 - v100);
    float c11 = v110 + fx * (v111 - v110);
    float c0 = c00 + fy * (c01 - c00);
    float c1 = c10 + fy * (c11 - c10);
    out[idx] = c0 + fz * (c1 - c0);
}

// ---------------------------------------------------------------------------
// Demon forces (dual), float4 over x: u = vf + diff*g/(|g|^2+diff^2).
// g = 0.5*(grad(warped)+grad(fixed)), jnp.gradient boundary rules.
// ---------------------------------------------------------------------------
__global__ void forces_kernel(const float* __restrict__ wpd,
                              const float* __restrict__ fix,
                              const float* __restrict__ vf,
                              float* __restrict__ u) {
    int t = blockIdx.x * blockDim.x + threadIdx.x;
    if (t >= N / 4) return;
    int idx = t << 2;
    int x0 = idx & 127, y = (idx >> 7) & 127, z = idx >> 14;

    float4 wc4 = *(const float4*)(wpd + idx);
    float4 fc4 = *(const float4*)(fix + idx);

    int iyp = (y < 127) ? idx + 128   : idx;
    int iym = (y > 0)   ? idx - 128   : idx;
    int izp = (z < 127) ? idx + 16384 : idx;
    int izm = (z > 0)   ? idx - 16384 : idx;

    float4 wyp = *(const float4*)(wpd + iyp), wym = *(const float4*)(wpd + iym);
    float4 wzp = *(const float4*)(wpd + izp), wzm = *(const float4*)(wpd + izm);
    float4 fyp = *(const float4*)(fix + iyp), fym = *(const float4*)(fix + iym);
    float4 fzp = *(const float4*)(fix + izp), fzm = *(const float4*)(fix + izm);

    float wl = (x0 > 0)   ? wpd[idx - 1] : 0.0f;
    float wr = (x0 < 124) ? wpd[idx + 4] : 0.0f;
    float fl = (x0 > 0)   ? fix[idx - 1] : 0.0f;
    float fr = (x0 < 124) ? fix[idx + 4] : 0.0f;

    float wcv[4] = {wc4.x, wc4.y, wc4.z, wc4.w};
    float fcv[4] = {fc4.x, fc4.y, fc4.z, fc4.w};
    float wypv[4] = {wyp.x, wyp.y, wyp.z, wyp.w};
    float wymv[4] = {wym.x, wym.y, wym.z, wym.w};
    float wzpv[4] = {wzp.x, wzp.y, wzp.z, wzp.w};
    float wzmv[4] = {wzm.x, wzm.y, wzm.z, wzm.w};
    float fypv[4] = {fyp.x, fyp.y, fyp.z, fyp.w};
    float fymv[4] = {fym.x, fym.y, fym.z, fym.w};
    float fzpv[4] = {fzp.x, fzp.y, fzp.z, fzp.w};
    float fzmv[4] = {fzm.x, fzm.y, fzm.z, fzm.w};

    float4 vz4 = *(const float4*)(vf + idx);
    float4 vy4 = *(const float4*)(vf + N + idx);
    float4 vx4 = *(const float4*)(vf + 2 * N + idx);
    float vzv[4] = {vz4.x, vz4.y, vz4.z, vz4.w};
    float vyv[4] = {vy4.x, vy4.y, vy4.z, vy4.w};
    float vxv[4] = {vx4.x, vx4.y, vx4.z, vx4.w};

    float oz[4], oy[4], ox[4];
#pragma unroll
    for (int i = 0; i < 4; ++i) {
        float wc = wcv[i], fc = fcv[i];
        float diff = wc - fc;

        float gwz = (z == 0)   ? (wzpv[i] - wc)
                  : (z == 127) ? (wc - wzmv[i])
                  : 0.5f * (wzpv[i] - wzmv[i]);
        float gfz = (z == 0)   ? (fzpv[i] - fc)
                  : (z == 127) ? (fc - fzmv[i])
                  : 0.5f * (fzpv[i] - fzmv[i]);
        float gz = 0.5f * (gwz + gfz);

        float gwy = (y == 0)   ? (wypv[i] - wc)
                  : (y == 127) ? (wc - wymv[i])
                  : 0.5f * (wypv[i] - wymv[i]);
        float gfy = (y == 0)   ? (fypv[i] - fc)
                  : (y == 127) ? (fc - fymv[i])
                  : 0.5f * (fypv[i] - fymv[i]);
        float gy = 0.5f * (gwy + gfy);

        float wleft  = (i == 0) ? wl : wcv[i - 1];
        float wright = (i == 3) ? wr : wcv[i + 1];
        float fleft  = (i == 0) ? fl : fcv[i - 1];
        float fright = (i == 3) ? fr : fcv[i + 1];
        int xi = x0 + i;
        float gwx = (xi == 0)   ? (wright - wc)
                  : (xi == 127) ? (wc - wleft)
                  : 0.5f * (wright - wleft);
        float gfx = (xi == 0)   ? (fright - fc)
                  : (xi == 127) ? (fc - fleft)
                  : 0.5f * (fright - fleft);
        float gx = 0.5f * (gwx + gfx);

        float denom = gz * gz + gy * gy + gx * gx + diff * diff;
        float s = (denom > EPS) ? (diff / denom) : 0.0f;

        oz[i] = vzv[i] + s * gz;
        oy[i] = vyv[i] + s * gy;
        ox[i] = vxv[i] + s * gx;
    }

    *(float4*)(u + idx)         = make_float4(oz[0], oz[1], oz[2], oz[3]);
    *(float4*)(u + N + idx)     = make_float4(oy[0], oy[1], oy[2], oy[3]);
    *(float4*)(u + 2 * N + idx) = make_float4(ox[0], ox[1], ox[2], ox[3]);
}

// ---------------------------------------------------------------------------
// Smooth pass 1: x-blur + y-blur fused, one z-plane + 32-row y-strip / block.
// x-blur in registers (3 overlapping float4 loads, zero-pad edges) -> LDS,
// one barrier, y-blur reads LDS float4 (conflict-free) -> global float4.
// LDS 38*128*4 = 19456 B -> 8 blocks/CU. Halo amp 38/32 = 1.19 (y only).
// ---------------------------------------------------------------------------
__global__ __launch_bounds__(256) void xy_blur_kernel(const float* __restrict__ in,
                                                      float* __restrict__ out) {
    int b = blockIdx.x;
    int c = b >> 9;               // channel (512 blocks per channel)
    int t = b & 511;
    int z = t & 127;
    int y0 = (t >> 7) << 5;       // 0,32,64,96
    const float* inp = in + (size_t)c * N + ((size_t)z << 14);
    float* outp = out + (size_t)c * N + ((size_t)z << 14);

    __shared__ float S[38 * 128];

    // stage 1: x-blur rows y0-3 .. y0+34 into S (zero rows outside volume)
    for (int e = threadIdx.x; e < 38 * 32; e += 256) {
        int x4 = e & 31;          // float4 index along x (0..31)
        int r  = e >> 5;          // row 0..37
        int gy = y0 + r - 3;
        float4 res = make_float4(0.0f, 0.0f, 0.0f, 0.0f);
        if (gy >= 0 && gy < 128) {
            const float* row = inp + (gy << 7);
            int xb = x4 << 2;
            float4 v0 = *(const float4*)(row + xb);
            float4 m1 = (x4 > 0)  ? *(const float4*)(row + xb - 4) : make_float4(0,0,0,0);
            float4 p1 = (x4 < 31) ? *(const float4*)(row + xb + 4) : make_float4(0,0,0,0);
            float w[12] = {m1.x, m1.y, m1.z, m1.w,
                           v0.x, v0.y, v0.z, v0.w,
                           p1.x, p1.y, p1.z, p1.w};
            float o[4];
#pragma unroll
            for (int i = 0; i < 4; ++i) {
                o[i] = W3 * (w[i + 1] + w[i + 7]) + W2 * (w[i + 2] + w[i + 6])
                     + W1 * (w[i + 3] + w[i + 5]) + W0 * w[i + 4];
            }
            res = make_float4(o[0], o[1], o[2], o[3]);
        }
        *(float4*)(S + (r << 7) + (x4 << 2)) = res;
    }
    __syncthreads();

    // stage 2: y-blur S -> global (4 float4 units per thread)
    for (int e = threadIdx.x; e < 32 * 32; e += 256) {
        int x4 = e & 31;
        int y  = e >> 5;          // 0..31
        const float* base = S + (y << 7) + (x4 << 2);
        float4 v0 = *(const float4*)(base);
        float4 v1 = *(const float4*)(base + (1 << 7));
        float4 v2 = *(const float4*)(base + (2 << 7));
        float4 v3 = *(const float4*)(base + (3 << 7));
        float4 v4 = *(const float4*)(base + (4 << 7));
        float4 v5 = *(const float4*)(base + (5 << 7));
        float4 v6 = *(const float4*)(base + (6 << 7));
        float4 acc;
        acc.x = W3 * (v0.x + v6.x) + W2 * (v1.x + v5.x) + W1 * (v2.x + v4.x) + W0 * v3.x;
        acc.y = W3 * (v0.y + v6.y) + W2 * (v1.y + v5.y) + W1 * (v2.y + v4.y) + W0 * v3.y;
        acc.z = W3 * (v0.z + v6.z) + W2 * (v1.z + v5.z) + W1 * (v2.z + v4.z) + W0 * v3.z;
        acc.w = W3 * (v0.w + v6.w) + W2 * (v1.w + v5.w) + W1 * (v2.w + v4.w) + W0 * v3.w;
        *(float4*)(outp + ((y0 + y) << 7) + (x4 << 2)) = acc;
    }
}

// ---------------------------------------------------------------------------
// Smooth pass 2: z-blur, register sliding window. Each thread owns one (x,y)
// column for a 32-z chunk: 38 independent coalesced loads -> 32 outputs.
// No LDS, no barriers. Grid 768 blocks x 256.
// ---------------------------------------------------------------------------
__global__ __launch_bounds__(256) void z_blur_kernel(const float* __restrict__ in,
                                                     float* __restrict__ out) {
    int g = blockIdx.x * 256 + threadIdx.x;   // 0 .. 196607
    int col  = g & 16383;                     // (y<<7)|x
    int rest = g >> 14;                       // 0..11
    int zc = rest & 3;                        // z-chunk
    int c  = rest >> 2;                       // channel
    int z0 = zc << 5;
    const float* inp = in + (size_t)c * N + col;
    float* outp = out + (size_t)c * N + col;

    float win[38];
#pragma unroll
    for (int i = 0; i < 38; ++i) {
        int zz = z0 - 3 + i;
        win[i] = (zz >= 0 && zz < 128) ? inp[(size_t)zz << 14] : 0.0f;
    }
#pragma unroll
    for (int k = 0; k < 32; ++k) {
        float acc = W3 * (win[k] + win[k + 6]) + W2 * (win[k + 1] + win[k + 5])
                  + W1 * (win[k + 2] + win[k + 4]) + W0 * win[k + 3];
        outp[(size_t)(z0 + k) << 14] = acc;
    }
}

extern "C" void kernel_launch(void* const* d_in, const int* in_sizes, int n_in,
                              void* d_out, int out_size, void* d_ws, size_t ws_size,
                              hipStream_t stream) {
    const float* mov = (const float*)d_in[0];
    const float* fix = (const float*)d_in[1];
    float* vf = (float*)d_out;          // (3, N) — lives in d_out throughout
    float* ws = (float*)d_ws;
    float* warped = ws;                 // N floats
    float* u      = ws + (size_t)N;     // 3N floats  (forces output)
    float* u2     = ws + (size_t)4 * N; // 3N floats  (xy-blur output)

    // vf0 = 0 (harness poisons d_out with 0xAA before every call)
    hipMemsetAsync(vf, 0, (size_t)3 * N * sizeof(float), stream);

    const int BLK = 256;
    const int gridN  = N / BLK;          // 8192
    const int gridF  = (N / 4) / BLK;    // 2048
    const int gridXY = 512 * 3;          // 1536
    const int gridZ  = (3 * N / 32) / BLK; // 768

    for (int it = 0; it < ITERS; ++it) {
        warp_kernel   <<<gridN,  BLK, 0, stream>>>(mov, vf, warped);
        forces_kernel <<<gridF,  BLK, 0, stream>>>(warped, fix, vf, u);
        xy_blur_kernel<<<gridXY, BLK, 0, stream>>>(u, u2);
        z_blur_kernel <<<gridZ,  BLK, 0, stream>>>(u2, vf);
    }
}